// Round 4
// baseline (206.161 us; speedup 1.0000x reference)
//
#include <hip/hip_runtime.h>

// pred/target (4,4,64,128,128) fp32 -> 16 volumes of 64x128x128.
#define NB 16
#define DD 64
#define HH 128
#define WW 128
#define HW (HH * WW)

constexpr int TH = 8;            // output rows per block
constexpr int CD = 8;            // output planes per block (D-chunk)
constexpr float INV_COUNT = 1.0f / 50331648.0f; // 1/(3*16*64*128*128)

__global__ void zero_out_kernel(float* out) {
    if (threadIdx.x == 0 && blockIdx.x == 0) out[0] = 0.0f;
}

__global__ __launch_bounds__(256, 4) void sobel_l1_kernel(
    const float* __restrict__ pred,
    const float* __restrict__ target,
    float* __restrict__ out)
{
    __shared__ float wsum[4];

    const int tid = threadIdx.x;
    int b = blockIdx.x;
    const int bh = b & 15; b >>= 4;     // 16 h-tiles
    const int bc = b & 7;  b >>= 3;     // 8 d-chunks
    const int bn = b;                   // 16 volumes

    const int h0 = bh * TH;
    const int d0 = bc * CD;
    const size_t nbase = (size_t)bn * (size_t)(DD * HW);

    const int tc = tid & 31;            // w-quad (lane in 32-lane row group)
    const int lh = tid >> 5;            // 0..7 output row within tile
    const int ghc = h0 + lh;            // this thread's output row

    // Row offsets (element units, within a plane) and validity for the 3 halo rows.
    int  rowoff[3];
    bool rowok[3];
#pragma unroll
    for (int r = 0; r < 3; ++r) {
        const int gh = ghc - 1 + r;
        rowok[r]  = (unsigned)gh < HH;
        rowoff[r] = gh * WW + 4 * tc;
    }

    // Per-plane partials for this thread's 4 outputs, straight from global:
    //   A = s(h)s(w)v, Bh = d(h)s(w)v, Bw = s(h)d(w)v   with v = p - q.
    auto plane_g = [&](int gd, float4& A_, float4& Bh_, float4& Bw_) {
        const bool zok = (unsigned)gd < DD;
        const size_t pb = nbase + (size_t)gd * HW;
        float4 rs[3], rdw[3];
#pragma unroll
        for (int r = 0; r < 3; ++r) {
            float4 v = float4{0.f, 0.f, 0.f, 0.f};
            if (zok && rowok[r]) {
                const size_t idx = pb + rowoff[r];
                const float4 p = *(const float4*)(pred + idx);
                const float4 q = *(const float4*)(target + idx);
                v = float4{p.x - q.x, p.y - q.y, p.z - q.z, p.w - q.w};
            }
            float lm = __shfl_up(v.w, 1, 32);
            float rp = __shfl_down(v.x, 1, 32);
            if (tc == 0)  lm = 0.f;     // w = -1: volume border
            if (tc == 31) rp = 0.f;     // w = 128: volume border
            rs[r]  = float4{lm  + 2.f * v.x + v.y,
                            v.x + 2.f * v.y + v.z,
                            v.y + 2.f * v.z + v.w,
                            v.z + 2.f * v.w + rp};
            rdw[r] = float4{v.y - lm, v.z - v.x, v.w - v.y, rp - v.z};
        }
        A_  = float4{rs[0].x + 2.f * rs[1].x + rs[2].x,
                     rs[0].y + 2.f * rs[1].y + rs[2].y,
                     rs[0].z + 2.f * rs[1].z + rs[2].z,
                     rs[0].w + 2.f * rs[1].w + rs[2].w};
        Bh_ = float4{rs[2].x - rs[0].x, rs[2].y - rs[0].y,
                     rs[2].z - rs[0].z, rs[2].w - rs[0].w};
        Bw_ = float4{rdw[0].x + 2.f * rdw[1].x + rdw[2].x,
                     rdw[0].y + 2.f * rdw[1].y + rdw[2].y,
                     rdw[0].z + 2.f * rdw[1].z + rdw[2].z,
                     rdw[0].w + 2.f * rdw[1].w + rdw[2].w};
    };

    float4 rA[3], rBh[3], rBw[3];
    plane_g(d0 - 1, rA[0], rBh[0], rBw[0]);
    plane_g(d0,     rA[1], rBh[1], rBw[1]);

    float acc = 0.0f;
#pragma unroll
    for (int ld = 0; ld < CD; ++ld) {
        const int s0 = ld % 3, s1 = (ld + 1) % 3, s2 = (ld + 2) % 3;
        plane_g(d0 + ld + 1, rA[s2], rBh[s2], rBw[s2]);

        const float4 a0 = rA[s0],  a2 = rA[s2];
        const float4 b0 = rBh[s0], b1 = rBh[s1], b2 = rBh[s2];
        const float4 c0 = rBw[s0], c1 = rBw[s1], c2 = rBw[s2];
        acc += fabsf(a2.x - a0.x) + fabsf(a2.y - a0.y)
             + fabsf(a2.z - a0.z) + fabsf(a2.w - a0.w);
        acc += fabsf(b0.x + 2.f * b1.x + b2.x) + fabsf(b0.y + 2.f * b1.y + b2.y)
             + fabsf(b0.z + 2.f * b1.z + b2.z) + fabsf(b0.w + 2.f * b1.w + b2.w);
        acc += fabsf(c0.x + 2.f * c1.x + c2.x) + fabsf(c0.y + 2.f * c1.y + c2.y)
             + fabsf(c0.z + 2.f * c1.z + c2.z) + fabsf(c0.w + 2.f * c1.w + c2.w);
    }

    // ---- block reduction (only sync in the kernel) ----
#pragma unroll
    for (int off = 32; off > 0; off >>= 1)
        acc += __shfl_down(acc, off, 64);
    const int wave = tid >> 6;
    if ((tid & 63) == 0) wsum[wave] = acc;
    __syncthreads();
    if (tid == 0) {
        const float s = wsum[0] + wsum[1] + wsum[2] + wsum[3];
        atomicAdd(out, s * INV_COUNT);
    }
}

extern "C" void kernel_launch(void* const* d_in, const int* in_sizes, int n_in,
                              void* d_out, int out_size, void* d_ws, size_t ws_size,
                              hipStream_t stream) {
    const float* pred   = (const float*)d_in[0];
    const float* target = (const float*)d_in[1];
    float* out = (float*)d_out;

    zero_out_kernel<<<1, 64, 0, stream>>>(out);

    // 16 volumes * 8 d-chunks * 16 h-tiles = 2048 blocks
    const int nblocks = NB * (DD / CD) * (HH / TH);
    sobel_l1_kernel<<<nblocks, 256, 0, stream>>>(pred, target, out);
}

// Round 5
// 187.344 us; speedup vs baseline: 1.1004x; 1.1004x over previous
//
#include <hip/hip_runtime.h>

// pred/target (4,4,64,128,128) fp32 -> 16 volumes of 64x128x128.
#define NB 16
#define DD 64
#define HH 128
#define WW 128
#define HW (HH * WW)

constexpr int TH = 8;            // output rows per block
constexpr int CD = 8;            // output planes per block (D-chunk)
constexpr float INV_COUNT = 1.0f / 50331648.0f; // 1/(3*16*64*128*128)

__global__ void zero_out_kernel(float* out) {
    if (threadIdx.x == 0 && blockIdx.x == 0) out[0] = 0.0f;
}

// NOTE: no min-waves arg — R4 showed __launch_bounds__(256,4) caps VGPR at 64
// and spills ~147 MB of scratch per dispatch. Let the allocator take ~128.
__global__ __launch_bounds__(256) void sobel_l1_kernel(
    const float* __restrict__ pred,
    const float* __restrict__ target,
    float* __restrict__ out)
{
    __shared__ float wsum[4];

    const int tid = threadIdx.x;
    int b = blockIdx.x;
    const int bh = b & 15; b >>= 4;     // 16 h-tiles
    const int bc = b & 7;  b >>= 3;     // 8 d-chunks
    const int bn = b;                   // 16 volumes

    const int h0 = bh * TH;
    const int d0 = bc * CD;
    const size_t nbase = (size_t)bn * (size_t)(DD * HW);

    const int tc = tid & 31;            // w-quad (lane in 32-lane row group)
    const int lh = tid >> 5;            // 0..7 output row within tile
    const int ghc = h0 + lh;            // this thread's output row

    // Row offsets (element units, within a plane) and validity for the 3 halo rows.
    int  rowoff[3];
    bool rowok[3];
#pragma unroll
    for (int r = 0; r < 3; ++r) {
        const int gh = ghc - 1 + r;
        rowok[r]  = (unsigned)gh < HH;
        rowoff[r] = gh * WW + 4 * tc;
    }

    // Per-plane partials for this thread's 4 outputs, straight from global:
    //   A = s(h)s(w)v, Bh = d(h)s(w)v, Bw = s(h)d(w)v   with v = p - q.
    auto plane_g = [&](int gd, float4& A_, float4& Bh_, float4& Bw_) {
        const bool zok = (unsigned)gd < DD;
        const size_t pb = nbase + (size_t)gd * HW;
        float4 rs[3], rdw[3];
#pragma unroll
        for (int r = 0; r < 3; ++r) {
            float4 v = float4{0.f, 0.f, 0.f, 0.f};
            if (zok && rowok[r]) {
                const size_t idx = pb + rowoff[r];
                const float4 p = *(const float4*)(pred + idx);
                const float4 q = *(const float4*)(target + idx);
                v = float4{p.x - q.x, p.y - q.y, p.z - q.z, p.w - q.w};
            }
            float lm = __shfl_up(v.w, 1, 32);
            float rp = __shfl_down(v.x, 1, 32);
            if (tc == 0)  lm = 0.f;     // w = -1: volume border
            if (tc == 31) rp = 0.f;     // w = 128: volume border
            rs[r]  = float4{lm  + 2.f * v.x + v.y,
                            v.x + 2.f * v.y + v.z,
                            v.y + 2.f * v.z + v.w,
                            v.z + 2.f * v.w + rp};
            rdw[r] = float4{v.y - lm, v.z - v.x, v.w - v.y, rp - v.z};
        }
        A_  = float4{rs[0].x + 2.f * rs[1].x + rs[2].x,
                     rs[0].y + 2.f * rs[1].y + rs[2].y,
                     rs[0].z + 2.f * rs[1].z + rs[2].z,
                     rs[0].w + 2.f * rs[1].w + rs[2].w};
        Bh_ = float4{rs[2].x - rs[0].x, rs[2].y - rs[0].y,
                     rs[2].z - rs[0].z, rs[2].w - rs[0].w};
        Bw_ = float4{rdw[0].x + 2.f * rdw[1].x + rdw[2].x,
                     rdw[0].y + 2.f * rdw[1].y + rdw[2].y,
                     rdw[0].z + 2.f * rdw[1].z + rdw[2].z,
                     rdw[0].w + 2.f * rdw[1].w + rdw[2].w};
    };

    float4 rA[3], rBh[3], rBw[3];
    plane_g(d0 - 1, rA[0], rBh[0], rBw[0]);
    plane_g(d0,     rA[1], rBh[1], rBw[1]);

    float acc = 0.0f;
#pragma unroll
    for (int ld = 0; ld < CD; ++ld) {
        const int s0 = ld % 3, s1 = (ld + 1) % 3, s2 = (ld + 2) % 3;
        plane_g(d0 + ld + 1, rA[s2], rBh[s2], rBw[s2]);

        const float4 a0 = rA[s0],  a2 = rA[s2];
        const float4 b0 = rBh[s0], b1 = rBh[s1], b2 = rBh[s2];
        const float4 c0 = rBw[s0], c1 = rBw[s1], c2 = rBw[s2];
        acc += fabsf(a2.x - a0.x) + fabsf(a2.y - a0.y)
             + fabsf(a2.z - a0.z) + fabsf(a2.w - a0.w);
        acc += fabsf(b0.x + 2.f * b1.x + b2.x) + fabsf(b0.y + 2.f * b1.y + b2.y)
             + fabsf(b0.z + 2.f * b1.z + b2.z) + fabsf(b0.w + 2.f * b1.w + b2.w);
        acc += fabsf(c0.x + 2.f * c1.x + c2.x) + fabsf(c0.y + 2.f * c1.y + c2.y)
             + fabsf(c0.z + 2.f * c1.z + c2.z) + fabsf(c0.w + 2.f * c1.w + c2.w);
    }

    // ---- block reduction (only sync in the kernel) ----
#pragma unroll
    for (int off = 32; off > 0; off >>= 1)
        acc += __shfl_down(acc, off, 64);
    const int wave = tid >> 6;
    if ((tid & 63) == 0) wsum[wave] = acc;
    __syncthreads();
    if (tid == 0) {
        const float s = wsum[0] + wsum[1] + wsum[2] + wsum[3];
        atomicAdd(out, s * INV_COUNT);
    }
}

extern "C" void kernel_launch(void* const* d_in, const int* in_sizes, int n_in,
                              void* d_out, int out_size, void* d_ws, size_t ws_size,
                              hipStream_t stream) {
    const float* pred   = (const float*)d_in[0];
    const float* target = (const float*)d_in[1];
    float* out = (float*)d_out;

    zero_out_kernel<<<1, 64, 0, stream>>>(out);

    // 16 volumes * 8 d-chunks * 16 h-tiles = 2048 blocks
    const int nblocks = NB * (DD / CD) * (HH / TH);
    sobel_l1_kernel<<<nblocks, 256, 0, stream>>>(pred, target, out);
}

// Round 6
// 178.645 us; speedup vs baseline: 1.1540x; 1.0487x over previous
//
#include <hip/hip_runtime.h>

// pred/target (4,4,64,128,128) fp32 -> 16 volumes of 64x128x128.
#define NB 16
#define DD 64
#define HH 128
#define WW 128
#define HW (HH * WW)

constexpr int CD = 4;                  // output planes per block
constexpr int TH = 8;                  // output rows per block
constexpr int LZ = CD + 2;             // 6 input planes
constexpr int LY = TH + 2;             // 10 input rows
constexpr int PL = LY * WW;            // LDS plane stride (floats) = 1280
constexpr int NPOS = LZ * LY * (WW / 4); // 1920 float4 slots
constexpr float INV_COUNT = 1.0f / 50331648.0f; // 1/(3*16*64*128*128)

__global__ void zero_out_kernel(float* out) {
    if (threadIdx.x == 0 && blockIdx.x == 0) out[0] = 0.0f;
}

__global__ __launch_bounds__(256) void sobel_l1_kernel(
    const float* __restrict__ pred,
    const float* __restrict__ target,
    float* __restrict__ out)
{
    __shared__ float t[LZ * PL];       // 6*10*128 floats = 30 KB
    __shared__ float wsum[4];

    const int tid = threadIdx.x;
    int b = blockIdx.x;
    const int bh = b & 15; b >>= 4;    // 16 h-tiles
    const int bc = b & 15; b >>= 4;    // 16 d-chunks
    const int bn = b;                  // 16 volumes

    const int h0 = bh * TH;
    const int d0 = bc * CD;
    const size_t nbase = (size_t)bn * (size_t)(DD * HW);

    // ---- one-shot tile load: all loads independent, clamped+masked ----
#pragma unroll
    for (int k = 0; k < 8; ++k) {
        const int i = k * 256 + tid;   // 0..2047; slots 0..1919 valid
        if (i < NPOS) {
            const int q4 = i & 31;
            const int ry = i >> 5;     // 0..59
            const int z  = ry / LY;
            const int y  = ry - z * LY;
            const int gd = d0 - 1 + z;
            const int gh = h0 - 1 + y;
            const bool ok = ((unsigned)gd < DD) && ((unsigned)gh < HH);
            const int gdc = min(max(gd, 0), DD - 1);
            const int ghc = min(max(gh, 0), HH - 1);
            const size_t idx = nbase + (size_t)gdc * HW + (size_t)ghc * WW + 4 * q4;
            const float4 p = *(const float4*)(pred + idx);
            const float4 q = *(const float4*)(target + idx);
            const float m = ok ? 1.0f : 0.0f;
            const float4 v = float4{(p.x - q.x) * m, (p.y - q.y) * m,
                                    (p.z - q.z) * m, (p.w - q.w) * m};
            *(float4*)&t[z * PL + y * WW + 4 * q4] = v;
        }
    }
    __syncthreads();                   // the only barrier before reduction

    // ---- compute from LDS: thread owns 4 w's of one h-row, marches z ----
    const int tc = tid & 31;           // w-quad
    const int lh = tid >> 5;           // 0..7 output row in tile

    // Per-plane partials: A = s(h)s(w)v, Bh = d(h)s(w)v, Bw = s(h)d(w)v.
    auto plane_l = [&](int z, float4& A_, float4& Bh_, float4& Bw_) {
        float4 rs[3], rdw[3];
#pragma unroll
        for (int r = 0; r < 3; ++r) {
            const float4 v = *(const float4*)&t[z * PL + (lh + r) * WW + 4 * tc];
            float lm = __shfl_up(v.w, 1, 32);
            float rp = __shfl_down(v.x, 1, 32);
            if (tc == 0)  lm = 0.f;    // w = -1: volume border
            if (tc == 31) rp = 0.f;    // w = 128: volume border
            rs[r]  = float4{lm  + 2.f * v.x + v.y,
                            v.x + 2.f * v.y + v.z,
                            v.y + 2.f * v.z + v.w,
                            v.z + 2.f * v.w + rp};
            rdw[r] = float4{v.y - lm, v.z - v.x, v.w - v.y, rp - v.z};
        }
        A_  = float4{rs[0].x + 2.f * rs[1].x + rs[2].x,
                     rs[0].y + 2.f * rs[1].y + rs[2].y,
                     rs[0].z + 2.f * rs[1].z + rs[2].z,
                     rs[0].w + 2.f * rs[1].w + rs[2].w};
        Bh_ = float4{rs[2].x - rs[0].x, rs[2].y - rs[0].y,
                     rs[2].z - rs[0].z, rs[2].w - rs[0].w};
        Bw_ = float4{rdw[0].x + 2.f * rdw[1].x + rdw[2].x,
                     rdw[0].y + 2.f * rdw[1].y + rdw[2].y,
                     rdw[0].z + 2.f * rdw[1].z + rdw[2].z,
                     rdw[0].w + 2.f * rdw[1].w + rdw[2].w};
    };

    float4 rA[3], rBh[3], rBw[3];
    plane_l(0, rA[0], rBh[0], rBw[0]);
    plane_l(1, rA[1], rBh[1], rBw[1]);

    float acc = 0.0f;
#pragma unroll
    for (int ld = 0; ld < CD; ++ld) {
        const int s0 = ld % 3, s1 = (ld + 1) % 3, s2 = (ld + 2) % 3;
        plane_l(ld + 2, rA[s2], rBh[s2], rBw[s2]);

        const float4 a0 = rA[s0],  a2 = rA[s2];
        const float4 b0 = rBh[s0], b1 = rBh[s1], b2 = rBh[s2];
        const float4 c0 = rBw[s0], c1 = rBw[s1], c2 = rBw[s2];
        acc += fabsf(a2.x - a0.x) + fabsf(a2.y - a0.y)
             + fabsf(a2.z - a0.z) + fabsf(a2.w - a0.w);
        acc += fabsf(b0.x + 2.f * b1.x + b2.x) + fabsf(b0.y + 2.f * b1.y + b2.y)
             + fabsf(b0.z + 2.f * b1.z + b2.z) + fabsf(b0.w + 2.f * b1.w + b2.w);
        acc += fabsf(c0.x + 2.f * c1.x + c2.x) + fabsf(c0.y + 2.f * c1.y + c2.y)
             + fabsf(c0.z + 2.f * c1.z + c2.z) + fabsf(c0.w + 2.f * c1.w + c2.w);
    }

    // ---- block reduction ----
#pragma unroll
    for (int off = 32; off > 0; off >>= 1)
        acc += __shfl_down(acc, off, 64);
    const int wave = tid >> 6;
    if ((tid & 63) == 0) wsum[wave] = acc;
    __syncthreads();
    if (tid == 0) {
        const float s = wsum[0] + wsum[1] + wsum[2] + wsum[3];
        atomicAdd(out, s * INV_COUNT);
    }
}

extern "C" void kernel_launch(void* const* d_in, const int* in_sizes, int n_in,
                              void* d_out, int out_size, void* d_ws, size_t ws_size,
                              hipStream_t stream) {
    const float* pred   = (const float*)d_in[0];
    const float* target = (const float*)d_in[1];
    float* out = (float*)d_out;

    zero_out_kernel<<<1, 64, 0, stream>>>(out);

    // 16 volumes * 16 d-chunks * 16 h-tiles = 4096 blocks
    const int nblocks = NB * (DD / CD) * (HH / TH);
    sobel_l1_kernel<<<nblocks, 256, 0, stream>>>(pred, target, out);
}